// Round 1
// baseline (137.646 us; speedup 1.0000x reference)
//
#include <hip/hip_runtime.h>

#define B_    4
#define N_    512
#define IND_  300
#define H_    128
#define QQ    8          // queries per attention block
#define KC    8          // k-chunks (partial sums, per-slice accum, no atomics)
#define RPB   4          // rows per prep block (weight-reuse factor)
#define LOG2E 1.4426950408889634f

// ---------------------------------------------------------------------------
// One fused packing kernel: transpose weights to [i/4][t][4] float4 tiles so
// prep's weight loads are coalesced dwordx4. Wa/Ua pre-scaled by log2e so
// prep can use raw exp2.
// ---------------------------------------------------------------------------
__global__ void pack_all(const float* __restrict__ Wx_w,
                         const float* __restrict__ Wa_w,
                         const float* __restrict__ Ua_w,
                         float* __restrict__ WxT4,
                         float* __restrict__ WaT4,
                         float* __restrict__ UaT4) {
    const int blk = blockIdx.x;
    const int t   = threadIdx.x;
    if (blk < IND_) {
        const int i = blk;
        WxT4[(i >> 2) * 512 + t * 4 + (i & 3)] = Wx_w[t * IND_ + i];
    } else if (blk < IND_ + H_) {
        const int i = blk - IND_;
        WaT4[(i >> 2) * 512 + t * 4 + (i & 3)] = Wa_w[t * H_ + i] * LOG2E;
    } else {
        const int i = blk - IND_ - H_;
        UaT4[(i >> 2) * 512 + t * 4 + (i & 3)] = Ua_w[t * H_ + i] * LOG2E;
    }
}

// ---------------------------------------------------------------------------
// Prep, row-batched RPB=4: each block computes 4 rows so every weight float4
// load from L2 is reused 4x (weight L2 traffic 573 MB -> 143 MB).
//   h = tanh(x.Wx^T + bx)
//   Eta = exp(h.Wa^T + ba)                 (per q,h — factored first exp)
//   kv  = {exp(h.Ua^T + bu), M, M*h, 0}    (M = exp(mask); M*h prefolded so
//                                           attn3's inner loop is 2 FMAs)
// ---------------------------------------------------------------------------
__global__ __launch_bounds__(128) void prep3(
    const float* __restrict__ x,      // [B*N, IND]
    const float* __restrict__ WxT4,   // packed [75][128][4]
    const float* __restrict__ Wx_b,
    const float* __restrict__ WaT4,   // packed [32][128][4], pre-scaled log2e
    const float* __restrict__ Wa_b,
    const float* __restrict__ UaT4,   // packed [32][128][4], pre-scaled log2e
    const float* __restrict__ Ua_b,
    const float* __restrict__ mask,   // [B*N, H]
    float* __restrict__ Eta,          // [B*N, H]
    float4* __restrict__ kv)          // [B*N, H] {Et, M, M*h, 0}
{
    __shared__ __align__(16) float xs[RPB][304];   // 304*4B row stride, 16B aligned
    __shared__ __align__(16) float hs[RPB][H_];

    const int r0 = blockIdx.x * RPB;
    const int t  = threadIdx.x;

    #pragma unroll
    for (int rr = 0; rr < RPB; ++rr) {
        const float* xrow = x + (size_t)(r0 + rr) * IND_;
        for (int i = t; i < IND_; i += 128) xs[rr][i] = xrow[i];
    }
    __syncthreads();

    const float4* w4 = (const float4*)WxT4 + t;
    const float bx = Wx_b[t];
    float acc[RPB];
    #pragma unroll
    for (int rr = 0; rr < RPB; ++rr) acc[rr] = bx;

    #pragma unroll 5
    for (int i4 = 0; i4 < IND_ / 4; ++i4) {
        float4 w = w4[i4 * 128];
        #pragma unroll
        for (int rr = 0; rr < RPB; ++rr) {
            float4 xv = *(const float4*)(&xs[rr][4 * i4]);   // lane-broadcast, conflict-free
            acc[rr] = fmaf(w.x, xv.x, acc[rr]);
            acc[rr] = fmaf(w.y, xv.y, acc[rr]);
            acc[rr] = fmaf(w.z, xv.z, acc[rr]);
            acc[rr] = fmaf(w.w, xv.w, acc[rr]);
        }
    }
    float hr[RPB];
    #pragma unroll
    for (int rr = 0; rr < RPB; ++rr) {
        hr[rr] = tanhf(acc[rr]);
        hs[rr][t] = hr[rr];
    }
    __syncthreads();

    const float4* wa4 = (const float4*)WaT4 + t;
    const float4* ua4 = (const float4*)UaT4 + t;
    const float ba = Wa_b[t] * LOG2E;
    const float bu = Ua_b[t] * LOG2E;
    float accA[RPB], accU[RPB];
    #pragma unroll
    for (int rr = 0; rr < RPB; ++rr) { accA[rr] = ba; accU[rr] = bu; }

    #pragma unroll 4
    for (int i4 = 0; i4 < H_ / 4; ++i4) {
        float4 wa = wa4[i4 * 128];
        float4 ua = ua4[i4 * 128];
        #pragma unroll
        for (int rr = 0; rr < RPB; ++rr) {
            float4 hv = *(const float4*)(&hs[rr][4 * i4]);
            accA[rr] = fmaf(wa.x, hv.x, accA[rr]);
            accA[rr] = fmaf(wa.y, hv.y, accA[rr]);
            accA[rr] = fmaf(wa.z, hv.z, accA[rr]);
            accA[rr] = fmaf(wa.w, hv.w, accA[rr]);
            accU[rr] = fmaf(ua.x, hv.x, accU[rr]);
            accU[rr] = fmaf(ua.y, hv.y, accU[rr]);
            accU[rr] = fmaf(ua.z, hv.z, accU[rr]);
            accU[rr] = fmaf(ua.w, hv.w, accU[rr]);
        }
    }

    #pragma unroll
    for (int rr = 0; rr < RPB; ++rr) {
        const size_t o = (size_t)(r0 + rr) * H_ + t;
        Eta[o] = __builtin_amdgcn_exp2f(accA[rr]);
        float M = __builtin_amdgcn_exp2f(mask[o] * LOG2E);
        kv[o]  = make_float4(__builtin_amdgcn_exp2f(accU[rr]), M, M * hr[rr], 0.f);
    }
}

// ---------------------------------------------------------------------------
// Attention inner loop, 7 VALU insts per score:
//   e  = Eta[q,h] * Et[k,h]              (= exp(ta+tb))
//   pn = exp2(e*log2e - log2e)           (= exp(e-1))
//   p0 = (e > 1) ? e : pn                (= exp(elu(ta+tb)))
//   l  += p0 * M        (fma)
//   cc += p0 * (M*hv)   (fma; M*hv prefolded in prep)
// Each block owns one k-chunk; partials land in its own accum slice.
// ---------------------------------------------------------------------------
__global__ __launch_bounds__(128) void attn3(
    const float* __restrict__ Eta,    // [B*N, H]
    const float4* __restrict__ kv,    // [B*N, H] {Et, M, M*hv, 0}
    float2* __restrict__ accum)       // [KC, B*N, H] {l, c}
{
    const int c  = blockIdx.x;        // 0..KC-1
    const int qg = blockIdx.y;        // 0..N/QQ-1
    const int b  = blockIdx.z;        // 0..B-1
    const int h  = threadIdx.x;
    const int q0 = qg * QQ;
    const int k0 = c * (N_ / KC);

    float eta[QQ], l[QQ], cc[QQ];
    #pragma unroll
    for (int j = 0; j < QQ; ++j) {
        eta[j] = Eta[((size_t)(b * N_ + q0 + j)) * H_ + h];
        l[j] = 0.f;
        cc[j] = 0.f;
    }

    const float4* kp = kv + ((size_t)(b * N_ + k0)) * H_ + h;

    #pragma unroll 4
    for (int k = 0; k < N_ / KC; ++k) {
        float4 v = kp[(size_t)k * H_];          // {Et, M, M*hv, 0}
        #pragma unroll
        for (int j = 0; j < QQ; ++j) {
            float e  = eta[j] * v.x;
            float pn = __builtin_amdgcn_exp2f(fmaf(e, LOG2E, -LOG2E));
            float p0 = (e > 1.f) ? e : pn;
            l[j]  = fmaf(p0, v.y, l[j]);
            cc[j] = fmaf(p0, v.z, cc[j]);
        }
    }

    #pragma unroll
    for (int j = 0; j < QQ; ++j) {
        accum[((size_t)c * (B_ * N_) + b * N_ + q0 + j) * H_ + h] =
            make_float2(l[j], cc[j]);
    }
}

__global__ void fin3(const float2* __restrict__ accum, float* __restrict__ out) {
    const int idx = blockIdx.x * 256 + threadIdx.x;   // B*N*H threads
    float L = 0.f, C = 0.f;
    #pragma unroll
    for (int c = 0; c < KC; ++c) {
        float2 a = accum[(size_t)c * (B_ * N_ * H_) + idx];
        L += a.x;
        C += a.y;
    }
    out[idx] = C / L;
}

extern "C" void kernel_launch(void* const* d_in, const int* in_sizes, int n_in,
                              void* d_out, int out_size, void* d_ws, size_t ws_size,
                              hipStream_t stream) {
    const float* word_vecs = (const float*)d_in[0];
    const float* mask      = (const float*)d_in[1];
    const float* Wx_w      = (const float*)d_in[2];
    const float* Wx_b      = (const float*)d_in[3];
    const float* Wa_w      = (const float*)d_in[4];
    const float* Wa_b      = (const float*)d_in[5];
    const float* Ua_w      = (const float*)d_in[6];
    const float* Ua_b      = (const float*)d_in[7];
    float* out = (float*)d_out;

    // workspace layout (16B aligned): ~21.3 MB total
    char* p = (char*)d_ws;
    float*  WxT4  = (float*)p;   p += (size_t)75 * 512 * 4;               // 153.6 KB
    float*  WaT4  = (float*)p;   p += (size_t)32 * 512 * 4;               // 64 KB
    float*  UaT4  = (float*)p;   p += (size_t)32 * 512 * 4;               // 64 KB
    float*  Eta   = (float*)p;   p += (size_t)B_ * N_ * H_ * 4;           // 1 MB
    float4* kv    = (float4*)p;  p += (size_t)B_ * N_ * H_ * 16;          // 4 MB
    float2* accum = (float2*)p;  p += (size_t)KC * B_ * N_ * H_ * 8;      // 16 MB

    pack_all<<<IND_ + 2 * H_, 128, 0, stream>>>(Wx_w, Wa_w, Ua_w, WxT4, WaT4, UaT4);

    prep3<<<(B_ * N_) / RPB, 128, 0, stream>>>(word_vecs, WxT4, Wx_b,
                                               WaT4, Wa_b, UaT4, Ua_b,
                                               mask, Eta, kv);

    dim3 grid(KC, N_ / QQ, B_);
    attn3<<<grid, 128, 0, stream>>>(Eta, kv, accum);

    fin3<<<(B_ * N_ * H_) / 256, 256, 0, stream>>>(accum, out);
}

// Round 2
// 126.244 us; speedup vs baseline: 1.0903x; 1.0903x over previous
//
#include <hip/hip_runtime.h>

#define B_    4
#define N_    512
#define IND_  300
#define H_    128
#define QQ    8          // queries per attention block
#define KC    8          // k-chunks (partial sums, per-slice accum, no atomics)
#define RPB   2          // rows per prep block (weight-reuse factor)
                         // RPB=4 (r1) -> 1 wave/SIMD, regressed; RPB=2 keeps 2/SIMD
#define LOG2E 1.4426950408889634f

// ---------------------------------------------------------------------------
// One fused packing kernel: transpose weights to [i/4][t][4] float4 tiles so
// prep's weight loads are coalesced dwordx4. Wa/Ua pre-scaled by log2e so
// prep can use raw exp2.
// ---------------------------------------------------------------------------
__global__ void pack_all(const float* __restrict__ Wx_w,
                         const float* __restrict__ Wa_w,
                         const float* __restrict__ Ua_w,
                         float* __restrict__ WxT4,
                         float* __restrict__ WaT4,
                         float* __restrict__ UaT4) {
    const int blk = blockIdx.x;
    const int t   = threadIdx.x;
    if (blk < IND_) {
        const int i = blk;
        WxT4[(i >> 2) * 512 + t * 4 + (i & 3)] = Wx_w[t * IND_ + i];
    } else if (blk < IND_ + H_) {
        const int i = blk - IND_;
        WaT4[(i >> 2) * 512 + t * 4 + (i & 3)] = Wa_w[t * H_ + i] * LOG2E;
    } else {
        const int i = blk - IND_ - H_;
        UaT4[(i >> 2) * 512 + t * 4 + (i & 3)] = Ua_w[t * H_ + i] * LOG2E;
    }
}

// ---------------------------------------------------------------------------
// Prep, row-batched RPB=2: each block computes 2 rows so every weight float4
// load from L2 is reused 2x (weight L2 traffic 573 MB -> 287 MB) while
// keeping 1024 blocks = 4 blocks/CU = 2 waves/SIMD occupancy.
//   h = tanh(x.Wx^T + bx)
//   Eta = exp(h.Wa^T + ba)                 (per q,h — factored first exp)
//   kv  = {exp(h.Ua^T + bu), M, M*h, 0}    (M = exp(mask); M*h prefolded so
//                                           attn3's inner loop is 2 FMAs)
// ---------------------------------------------------------------------------
__global__ __launch_bounds__(128) void prep3(
    const float* __restrict__ x,      // [B*N, IND]
    const float* __restrict__ WxT4,   // packed [75][128][4]
    const float* __restrict__ Wx_b,
    const float* __restrict__ WaT4,   // packed [32][128][4], pre-scaled log2e
    const float* __restrict__ Wa_b,
    const float* __restrict__ UaT4,   // packed [32][128][4], pre-scaled log2e
    const float* __restrict__ Ua_b,
    const float* __restrict__ mask,   // [B*N, H]
    float* __restrict__ Eta,          // [B*N, H]
    float4* __restrict__ kv)          // [B*N, H] {Et, M, M*h, 0}
{
    __shared__ __align__(16) float xs[RPB][304];   // 304*4B row stride, 16B aligned
    __shared__ __align__(16) float hs[RPB][H_];

    const int r0 = blockIdx.x * RPB;
    const int t  = threadIdx.x;

    #pragma unroll
    for (int rr = 0; rr < RPB; ++rr) {
        const float* xrow = x + (size_t)(r0 + rr) * IND_;
        for (int i = t; i < IND_; i += 128) xs[rr][i] = xrow[i];
    }
    __syncthreads();

    const float4* w4 = (const float4*)WxT4 + t;
    const float bx = Wx_b[t];
    float acc[RPB];
    #pragma unroll
    for (int rr = 0; rr < RPB; ++rr) acc[rr] = bx;

    #pragma unroll 5
    for (int i4 = 0; i4 < IND_ / 4; ++i4) {
        float4 w = w4[i4 * 128];
        #pragma unroll
        for (int rr = 0; rr < RPB; ++rr) {
            float4 xv = *(const float4*)(&xs[rr][4 * i4]);   // lane-broadcast, conflict-free
            acc[rr] = fmaf(w.x, xv.x, acc[rr]);
            acc[rr] = fmaf(w.y, xv.y, acc[rr]);
            acc[rr] = fmaf(w.z, xv.z, acc[rr]);
            acc[rr] = fmaf(w.w, xv.w, acc[rr]);
        }
    }
    float hr[RPB];
    #pragma unroll
    for (int rr = 0; rr < RPB; ++rr) {
        hr[rr] = tanhf(acc[rr]);
        hs[rr][t] = hr[rr];
    }
    __syncthreads();

    const float4* wa4 = (const float4*)WaT4 + t;
    const float4* ua4 = (const float4*)UaT4 + t;
    const float ba = Wa_b[t] * LOG2E;
    const float bu = Ua_b[t] * LOG2E;
    float accA[RPB], accU[RPB];
    #pragma unroll
    for (int rr = 0; rr < RPB; ++rr) { accA[rr] = ba; accU[rr] = bu; }

    #pragma unroll 4
    for (int i4 = 0; i4 < H_ / 4; ++i4) {
        float4 wa = wa4[i4 * 128];
        float4 ua = ua4[i4 * 128];
        #pragma unroll
        for (int rr = 0; rr < RPB; ++rr) {
            float4 hv = *(const float4*)(&hs[rr][4 * i4]);
            accA[rr] = fmaf(wa.x, hv.x, accA[rr]);
            accA[rr] = fmaf(wa.y, hv.y, accA[rr]);
            accA[rr] = fmaf(wa.z, hv.z, accA[rr]);
            accA[rr] = fmaf(wa.w, hv.w, accA[rr]);
            accU[rr] = fmaf(ua.x, hv.x, accU[rr]);
            accU[rr] = fmaf(ua.y, hv.y, accU[rr]);
            accU[rr] = fmaf(ua.z, hv.z, accU[rr]);
            accU[rr] = fmaf(ua.w, hv.w, accU[rr]);
        }
    }

    #pragma unroll
    for (int rr = 0; rr < RPB; ++rr) {
        const size_t o = (size_t)(r0 + rr) * H_ + t;
        Eta[o] = __builtin_amdgcn_exp2f(accA[rr]);
        float M = __builtin_amdgcn_exp2f(mask[o] * LOG2E);
        kv[o]  = make_float4(__builtin_amdgcn_exp2f(accU[rr]), M, M * hr[rr], 0.f);
    }
}

// ---------------------------------------------------------------------------
// Attention inner loop, 7 VALU insts per score:
//   e  = Eta[q,h] * Et[k,h]              (= exp(ta+tb))
//   pn = exp2(e*log2e - log2e)           (= exp(e-1))
//   p0 = (e > 1) ? e : pn                (= exp(elu(ta+tb)))
//   l  += p0 * M        (fma)
//   cc += p0 * (M*hv)   (fma; M*hv prefolded in prep)
// Each block owns one k-chunk; partials land in its own accum slice.
// ---------------------------------------------------------------------------
__global__ __launch_bounds__(128) void attn3(
    const float* __restrict__ Eta,    // [B*N, H]
    const float4* __restrict__ kv,    // [B*N, H] {Et, M, M*hv, 0}
    float2* __restrict__ accum)       // [KC, B*N, H] {l, c}
{
    const int c  = blockIdx.x;        // 0..KC-1
    const int qg = blockIdx.y;        // 0..N/QQ-1
    const int b  = blockIdx.z;        // 0..B-1
    const int h  = threadIdx.x;
    const int q0 = qg * QQ;
    const int k0 = c * (N_ / KC);

    float eta[QQ], l[QQ], cc[QQ];
    #pragma unroll
    for (int j = 0; j < QQ; ++j) {
        eta[j] = Eta[((size_t)(b * N_ + q0 + j)) * H_ + h];
        l[j] = 0.f;
        cc[j] = 0.f;
    }

    const float4* kp = kv + ((size_t)(b * N_ + k0)) * H_ + h;

    #pragma unroll 4
    for (int k = 0; k < N_ / KC; ++k) {
        float4 v = kp[(size_t)k * H_];          // {Et, M, M*hv, 0}
        #pragma unroll
        for (int j = 0; j < QQ; ++j) {
            float e  = eta[j] * v.x;
            float pn = __builtin_amdgcn_exp2f(fmaf(e, LOG2E, -LOG2E));
            float p0 = (e > 1.f) ? e : pn;
            l[j]  = fmaf(p0, v.y, l[j]);
            cc[j] = fmaf(p0, v.z, cc[j]);
        }
    }

    #pragma unroll
    for (int j = 0; j < QQ; ++j) {
        accum[((size_t)c * (B_ * N_) + b * N_ + q0 + j) * H_ + h] =
            make_float2(l[j], cc[j]);
    }
}

__global__ void fin3(const float2* __restrict__ accum, float* __restrict__ out) {
    const int idx = blockIdx.x * 256 + threadIdx.x;   // B*N*H threads
    float L = 0.f, C = 0.f;
    #pragma unroll
    for (int c = 0; c < KC; ++c) {
        float2 a = accum[(size_t)c * (B_ * N_ * H_) + idx];
        L += a.x;
        C += a.y;
    }
    out[idx] = C / L;
}

extern "C" void kernel_launch(void* const* d_in, const int* in_sizes, int n_in,
                              void* d_out, int out_size, void* d_ws, size_t ws_size,
                              hipStream_t stream) {
    const float* word_vecs = (const float*)d_in[0];
    const float* mask      = (const float*)d_in[1];
    const float* Wx_w      = (const float*)d_in[2];
    const float* Wx_b      = (const float*)d_in[3];
    const float* Wa_w      = (const float*)d_in[4];
    const float* Wa_b      = (const float*)d_in[5];
    const float* Ua_w      = (const float*)d_in[6];
    const float* Ua_b      = (const float*)d_in[7];
    float* out = (float*)d_out;

    // workspace layout (16B aligned): ~21.3 MB total
    char* p = (char*)d_ws;
    float*  WxT4  = (float*)p;   p += (size_t)75 * 512 * 4;               // 153.6 KB
    float*  WaT4  = (float*)p;   p += (size_t)32 * 512 * 4;               // 64 KB
    float*  UaT4  = (float*)p;   p += (size_t)32 * 512 * 4;               // 64 KB
    float*  Eta   = (float*)p;   p += (size_t)B_ * N_ * H_ * 4;           // 1 MB
    float4* kv    = (float4*)p;  p += (size_t)B_ * N_ * H_ * 16;          // 4 MB
    float2* accum = (float2*)p;  p += (size_t)KC * B_ * N_ * H_ * 8;      // 16 MB

    pack_all<<<IND_ + 2 * H_, 128, 0, stream>>>(Wx_w, Wa_w, Ua_w, WxT4, WaT4, UaT4);

    prep3<<<(B_ * N_) / RPB, 128, 0, stream>>>(word_vecs, WxT4, Wx_b,
                                               WaT4, Wa_b, UaT4, Ua_b,
                                               mask, Eta, kv);

    dim3 grid(KC, N_ / QQ, B_);
    attn3<<<grid, 128, 0, stream>>>(Eta, kv, accum);

    fin3<<<(B_ * N_ * H_) / 256, 256, 0, stream>>>(accum, out);
}

// Round 3
// 125.722 us; speedup vs baseline: 1.0948x; 1.0042x over previous
//
#include <hip/hip_runtime.h>

#define B_    4
#define N_    512
#define IND_  300
#define H_    128
#define QQ    8          // queries per attention block
#define KC    8          // k-chunks (partial sums, per-slice accum, no atomics)
#define RPB   4          // rows per prep block (2 per 128-thread group)
#define LOG2E 1.4426950408889634f

// ---------------------------------------------------------------------------
// One fused packing kernel: transpose weights to [i/4][t][4] float4 tiles so
// prep's weight loads are coalesced dwordx4. Wa/Ua pre-scaled by log2e so
// prep can use raw exp2.
// ---------------------------------------------------------------------------
__global__ void pack_all(const float* __restrict__ Wx_w,
                         const float* __restrict__ Wa_w,
                         const float* __restrict__ Ua_w,
                         float* __restrict__ WxT4,
                         float* __restrict__ WaT4,
                         float* __restrict__ UaT4) {
    const int blk = blockIdx.x;
    const int t   = threadIdx.x;
    if (blk < IND_) {
        const int i = blk;
        WxT4[(i >> 2) * 512 + t * 4 + (i & 3)] = Wx_w[t * IND_ + i];
    } else if (blk < IND_ + H_) {
        const int i = blk - IND_;
        WaT4[(i >> 2) * 512 + t * 4 + (i & 3)] = Wa_w[t * H_ + i] * LOG2E;
    } else {
        const int i = blk - IND_ - H_;
        UaT4[(i >> 2) * 512 + t * 4 + (i & 3)] = Ua_w[t * H_ + i] * LOG2E;
    }
}

// ---------------------------------------------------------------------------
// Prep, RPB=4 via 256-thread blocks: two 128-thread groups per block, each
// owning 2 rows. Both groups issue the SAME weight address stream in phase
// (barrier-synced), so group 1's weight reads hit L1 — per-block weight
// fetch from L2 is ~1x for 4 rows (L2 traffic 287 MB -> ~150 MB) while
// keeping 512 blocks x 4 waves = 2 waves/SIMD occupancy (RPB=2's level).
//   h = tanh(x.Wx^T + bx)
//   Eta = exp(h.Wa^T + ba)                 (per q,h — factored first exp)
//   kv  = {exp(h.Ua^T + bu), M, M*h, 0}    (M = exp(mask); M*h prefolded so
//                                           attn3's inner loop is 2 FMAs)
// ---------------------------------------------------------------------------
__global__ __launch_bounds__(256) void prep3(
    const float* __restrict__ x,      // [B*N, IND]
    const float* __restrict__ WxT4,   // packed [75][128][4]
    const float* __restrict__ Wx_b,
    const float* __restrict__ WaT4,   // packed [32][128][4], pre-scaled log2e
    const float* __restrict__ Wa_b,
    const float* __restrict__ UaT4,   // packed [32][128][4], pre-scaled log2e
    const float* __restrict__ Ua_b,
    const float* __restrict__ mask,   // [B*N, H]
    float* __restrict__ Eta,          // [B*N, H]
    float4* __restrict__ kv)          // [B*N, H] {Et, M, M*h, 0}
{
    __shared__ __align__(16) float xs[RPB][304];   // 304*4B row stride, 16B aligned
    __shared__ __align__(16) float hs[RPB][H_];

    const int r0 = blockIdx.x * RPB;
    const int t  = threadIdx.x;
    const int g  = t >> 7;            // group 0/1
    const int tt = t & 127;           // h index within group
    const int lr = 2 * g;             // group's first local row

    // all 256 threads cooperatively stage the 4 input rows
    #pragma unroll
    for (int rr = 0; rr < RPB; ++rr) {
        const float* xrow = x + (size_t)(r0 + rr) * IND_;
        for (int i = t; i < IND_; i += 256) xs[rr][i] = xrow[i];
    }
    __syncthreads();

    const float4* w4 = (const float4*)WxT4 + tt;
    const float bx = Wx_b[tt];
    float acc[2];
    acc[0] = bx;
    acc[1] = bx;

    #pragma unroll 5
    for (int i4 = 0; i4 < IND_ / 4; ++i4) {
        float4 w = w4[i4 * 128];      // identical stream in both groups -> L1 hit
        #pragma unroll
        for (int rr = 0; rr < 2; ++rr) {
            float4 xv = *(const float4*)(&xs[lr + rr][4 * i4]);  // lane-broadcast
            acc[rr] = fmaf(w.x, xv.x, acc[rr]);
            acc[rr] = fmaf(w.y, xv.y, acc[rr]);
            acc[rr] = fmaf(w.z, xv.z, acc[rr]);
            acc[rr] = fmaf(w.w, xv.w, acc[rr]);
        }
    }
    float hr[2];
    #pragma unroll
    for (int rr = 0; rr < 2; ++rr) {
        hr[rr] = tanhf(acc[rr]);
        hs[lr + rr][tt] = hr[rr];
    }
    __syncthreads();

    const float4* wa4 = (const float4*)WaT4 + tt;
    const float4* ua4 = (const float4*)UaT4 + tt;
    const float ba = Wa_b[tt] * LOG2E;
    const float bu = Ua_b[tt] * LOG2E;
    float accA[2], accU[2];
    accA[0] = ba; accA[1] = ba;
    accU[0] = bu; accU[1] = bu;

    #pragma unroll 4
    for (int i4 = 0; i4 < H_ / 4; ++i4) {
        float4 wa = wa4[i4 * 128];    // shared stream -> L1 hit for 2nd group
        float4 ua = ua4[i4 * 128];
        #pragma unroll
        for (int rr = 0; rr < 2; ++rr) {
            float4 hv = *(const float4*)(&hs[lr + rr][4 * i4]);
            accA[rr] = fmaf(wa.x, hv.x, accA[rr]);
            accA[rr] = fmaf(wa.y, hv.y, accA[rr]);
            accA[rr] = fmaf(wa.z, hv.z, accA[rr]);
            accA[rr] = fmaf(wa.w, hv.w, accA[rr]);
            accU[rr] = fmaf(ua.x, hv.x, accU[rr]);
            accU[rr] = fmaf(ua.y, hv.y, accU[rr]);
            accU[rr] = fmaf(ua.z, hv.z, accU[rr]);
            accU[rr] = fmaf(ua.w, hv.w, accU[rr]);
        }
    }

    #pragma unroll
    for (int rr = 0; rr < 2; ++rr) {
        const size_t o = (size_t)(r0 + lr + rr) * H_ + tt;
        Eta[o] = __builtin_amdgcn_exp2f(accA[rr]);
        float M = __builtin_amdgcn_exp2f(mask[o] * LOG2E);
        kv[o]  = make_float4(__builtin_amdgcn_exp2f(accU[rr]), M, M * hr[rr], 0.f);
    }
}

// ---------------------------------------------------------------------------
// Attention inner loop, 7 VALU insts per score (instruction floor for this
// algorithm — all reformulations checked land at 7):
//   e  = Eta[q,h] * Et[k,h]              (= exp(ta+tb))
//   pn = exp2(e*log2e - log2e)           (= exp(e-1))
//   p0 = (e > 1) ? e : pn                (= exp(elu(ta+tb)))
//   l  += p0 * M        (fma)
//   cc += p0 * (M*hv)   (fma; M*hv prefolded in prep)
// Each block owns one k-chunk; partials land in its own accum slice.
// ---------------------------------------------------------------------------
__global__ __launch_bounds__(128) void attn3(
    const float* __restrict__ Eta,    // [B*N, H]
    const float4* __restrict__ kv,    // [B*N, H] {Et, M, M*hv, 0}
    float2* __restrict__ accum)       // [KC, B*N, H] {l, c}
{
    const int c  = blockIdx.x;        // 0..KC-1
    const int qg = blockIdx.y;        // 0..N/QQ-1
    const int b  = blockIdx.z;        // 0..B-1
    const int h  = threadIdx.x;
    const int q0 = qg * QQ;
    const int k0 = c * (N_ / KC);

    float eta[QQ], l[QQ], cc[QQ];
    #pragma unroll
    for (int j = 0; j < QQ; ++j) {
        eta[j] = Eta[((size_t)(b * N_ + q0 + j)) * H_ + h];
        l[j] = 0.f;
        cc[j] = 0.f;
    }

    const float4* kp = kv + ((size_t)(b * N_ + k0)) * H_ + h;

    #pragma unroll 4
    for (int k = 0; k < N_ / KC; ++k) {
        float4 v = kp[(size_t)k * H_];          // {Et, M, M*hv, 0}
        #pragma unroll
        for (int j = 0; j < QQ; ++j) {
            float e  = eta[j] * v.x;
            float pn = __builtin_amdgcn_exp2f(fmaf(e, LOG2E, -LOG2E));
            float p0 = (e > 1.f) ? e : pn;
            l[j]  = fmaf(p0, v.y, l[j]);
            cc[j] = fmaf(p0, v.z, cc[j]);
        }
    }

    #pragma unroll
    for (int j = 0; j < QQ; ++j) {
        accum[((size_t)c * (B_ * N_) + b * N_ + q0 + j) * H_ + h] =
            make_float2(l[j], cc[j]);
    }
}

__global__ void fin3(const float2* __restrict__ accum, float* __restrict__ out) {
    const int idx = blockIdx.x * 256 + threadIdx.x;   // B*N*H threads
    float L = 0.f, C = 0.f;
    #pragma unroll
    for (int c = 0; c < KC; ++c) {
        float2 a = accum[(size_t)c * (B_ * N_ * H_) + idx];
        L += a.x;
        C += a.y;
    }
    out[idx] = C / L;
}

extern "C" void kernel_launch(void* const* d_in, const int* in_sizes, int n_in,
                              void* d_out, int out_size, void* d_ws, size_t ws_size,
                              hipStream_t stream) {
    const float* word_vecs = (const float*)d_in[0];
    const float* mask      = (const float*)d_in[1];
    const float* Wx_w      = (const float*)d_in[2];
    const float* Wx_b      = (const float*)d_in[3];
    const float* Wa_w      = (const float*)d_in[4];
    const float* Wa_b      = (const float*)d_in[5];
    const float* Ua_w      = (const float*)d_in[6];
    const float* Ua_b      = (const float*)d_in[7];
    float* out = (float*)d_out;

    // workspace layout (16B aligned): ~21.3 MB total
    char* p = (char*)d_ws;
    float*  WxT4  = (float*)p;   p += (size_t)75 * 512 * 4;               // 153.6 KB
    float*  WaT4  = (float*)p;   p += (size_t)32 * 512 * 4;               // 64 KB
    float*  UaT4  = (float*)p;   p += (size_t)32 * 512 * 4;               // 64 KB
    float*  Eta   = (float*)p;   p += (size_t)B_ * N_ * H_ * 4;           // 1 MB
    float4* kv    = (float4*)p;  p += (size_t)B_ * N_ * H_ * 16;          // 4 MB
    float2* accum = (float2*)p;  p += (size_t)KC * B_ * N_ * H_ * 8;      // 16 MB

    pack_all<<<IND_ + 2 * H_, 128, 0, stream>>>(Wx_w, Wa_w, Ua_w, WxT4, WaT4, UaT4);

    prep3<<<(B_ * N_) / RPB, 256, 0, stream>>>(word_vecs, WxT4, Wx_b,
                                               WaT4, Wa_b, UaT4, Ua_b,
                                               mask, Eta, kv);

    dim3 grid(KC, N_ / QQ, B_);
    attn3<<<grid, 128, 0, stream>>>(Eta, kv, accum);

    fin3<<<(B_ * N_ * H_) / 256, 256, 0, stream>>>(accum, out);
}

// Round 4
// 120.700 us; speedup vs baseline: 1.1404x; 1.0416x over previous
//
#include <hip/hip_runtime.h>

#define B_    4
#define N_    512
#define IND_  300
#define H_    128
#define QQ    8          // queries per attention block (even: paired for pk ops)
#define KC    8          // k-chunks (partial sums, per-slice accum, no atomics)
#define RPB   4          // rows per prep block (2 per 128-thread group)
#define LOG2E 1.4426950408889634f

typedef float v2f __attribute__((ext_vector_type(2)));

// ---------------------------------------------------------------------------
// One fused packing kernel: transpose weights to [i/4][t][4] float4 tiles so
// prep's weight loads are coalesced dwordx4. Wa/Ua pre-scaled by log2e so
// prep can use raw exp2.
// ---------------------------------------------------------------------------
__global__ void pack_all(const float* __restrict__ Wx_w,
                         const float* __restrict__ Wa_w,
                         const float* __restrict__ Ua_w,
                         float* __restrict__ WxT4,
                         float* __restrict__ WaT4,
                         float* __restrict__ UaT4) {
    const int blk = blockIdx.x;
    const int t   = threadIdx.x;
    if (blk < IND_) {
        const int i = blk;
        WxT4[(i >> 2) * 512 + t * 4 + (i & 3)] = Wx_w[t * IND_ + i];
    } else if (blk < IND_ + H_) {
        const int i = blk - IND_;
        WaT4[(i >> 2) * 512 + t * 4 + (i & 3)] = Wa_w[t * H_ + i] * LOG2E;
    } else {
        const int i = blk - IND_ - H_;
        UaT4[(i >> 2) * 512 + t * 4 + (i & 3)] = Ua_w[t * H_ + i] * LOG2E;
    }
}

// ---------------------------------------------------------------------------
// Prep, RPB=4 via 256-thread blocks: two 128-thread groups per block, each
// owning 2 rows; both groups share the weight stream (L1 hits). 512 blocks
// = 2 waves/SIMD. (r3: traffic cut beyond RPB=2 is ~neutral — prep3 is at
// its latency/VALU floor; do not touch further.)
// ---------------------------------------------------------------------------
__global__ __launch_bounds__(256) void prep3(
    const float* __restrict__ x,      // [B*N, IND]
    const float* __restrict__ WxT4,   // packed [75][128][4]
    const float* __restrict__ Wx_b,
    const float* __restrict__ WaT4,   // packed [32][128][4], pre-scaled log2e
    const float* __restrict__ Wa_b,
    const float* __restrict__ UaT4,   // packed [32][128][4], pre-scaled log2e
    const float* __restrict__ Ua_b,
    const float* __restrict__ mask,   // [B*N, H]
    float* __restrict__ Eta,          // [B*N, H]
    float4* __restrict__ kv)          // [B*N, H] {Et, M, M*h, 0}
{
    __shared__ __align__(16) float xs[RPB][304];   // 304*4B row stride, 16B aligned
    __shared__ __align__(16) float hs[RPB][H_];

    const int r0 = blockIdx.x * RPB;
    const int t  = threadIdx.x;
    const int g  = t >> 7;            // group 0/1
    const int tt = t & 127;           // h index within group
    const int lr = 2 * g;             // group's first local row

    // all 256 threads cooperatively stage the 4 input rows
    #pragma unroll
    for (int rr = 0; rr < RPB; ++rr) {
        const float* xrow = x + (size_t)(r0 + rr) * IND_;
        for (int i = t; i < IND_; i += 256) xs[rr][i] = xrow[i];
    }
    __syncthreads();

    const float4* w4 = (const float4*)WxT4 + tt;
    const float bx = Wx_b[tt];
    float acc[2];
    acc[0] = bx;
    acc[1] = bx;

    #pragma unroll 5
    for (int i4 = 0; i4 < IND_ / 4; ++i4) {
        float4 w = w4[i4 * 128];      // identical stream in both groups -> L1 hit
        #pragma unroll
        for (int rr = 0; rr < 2; ++rr) {
            float4 xv = *(const float4*)(&xs[lr + rr][4 * i4]);  // lane-broadcast
            acc[rr] = fmaf(w.x, xv.x, acc[rr]);
            acc[rr] = fmaf(w.y, xv.y, acc[rr]);
            acc[rr] = fmaf(w.z, xv.z, acc[rr]);
            acc[rr] = fmaf(w.w, xv.w, acc[rr]);
        }
    }
    float hr[2];
    #pragma unroll
    for (int rr = 0; rr < 2; ++rr) {
        hr[rr] = tanhf(acc[rr]);
        hs[lr + rr][tt] = hr[rr];
    }
    __syncthreads();

    const float4* wa4 = (const float4*)WaT4 + tt;
    const float4* ua4 = (const float4*)UaT4 + tt;
    const float ba = Wa_b[tt] * LOG2E;
    const float bu = Ua_b[tt] * LOG2E;
    float accA[2], accU[2];
    accA[0] = ba; accA[1] = ba;
    accU[0] = bu; accU[1] = bu;

    #pragma unroll 4
    for (int i4 = 0; i4 < H_ / 4; ++i4) {
        float4 wa = wa4[i4 * 128];    // shared stream -> L1 hit for 2nd group
        float4 ua = ua4[i4 * 128];
        #pragma unroll
        for (int rr = 0; rr < 2; ++rr) {
            float4 hv = *(const float4*)(&hs[lr + rr][4 * i4]);
            accA[rr] = fmaf(wa.x, hv.x, accA[rr]);
            accA[rr] = fmaf(wa.y, hv.y, accA[rr]);
            accA[rr] = fmaf(wa.z, hv.z, accA[rr]);
            accA[rr] = fmaf(wa.w, hv.w, accA[rr]);
            accU[rr] = fmaf(ua.x, hv.x, accU[rr]);
            accU[rr] = fmaf(ua.y, hv.y, accU[rr]);
            accU[rr] = fmaf(ua.z, hv.z, accU[rr]);
            accU[rr] = fmaf(ua.w, hv.w, accU[rr]);
        }
    }

    #pragma unroll
    for (int rr = 0; rr < 2; ++rr) {
        const size_t o = (size_t)(r0 + lr + rr) * H_ + tt;
        Eta[o] = __builtin_amdgcn_exp2f(accA[rr]);
        float M = __builtin_amdgcn_exp2f(mask[o] * LOG2E);
        kv[o]  = make_float4(__builtin_amdgcn_exp2f(accU[rr]), M, M * hr[rr], 0.f);
    }
}

// ---------------------------------------------------------------------------
// Attention inner loop, packed-f32 on query pairs:
//   e2  = eta2 * Et            (v_pk_mul_f32)
//   a2  = e2*log2e - log2e     (v_pk_fma_f32)
//   pn  = exp2(a2)             (2x v_exp_f32 — only scalar ops left)
//   p0  = med3(1, e, pn)       (v_med3_f32; == (e>1)?e:exp(e-1) since
//                               exp(e-1)>=e always and pn<=1 iff e<=1;
//                               pn=+inf overflow still yields e)
//   l2  += p0 * M              (v_pk_fma_f32)
//   cc2 += p0 * (M*hv)         (v_pk_fma_f32)
// Per 2 scores: 4 pk + 2 exp + 2 med3 = 28 cyc vs 40 scalar.
// ---------------------------------------------------------------------------
__global__ __launch_bounds__(128) void attn3(
    const float* __restrict__ Eta,    // [B*N, H]
    const float4* __restrict__ kv,    // [B*N, H] {Et, M, M*hv, 0}
    float2* __restrict__ accum)       // [KC, B*N, H] {l, c}
{
    const int c  = blockIdx.x;        // 0..KC-1
    const int qg = blockIdx.y;        // 0..N/QQ-1
    const int b  = blockIdx.z;        // 0..B-1
    const int h  = threadIdx.x;
    const int q0 = qg * QQ;
    const int k0 = c * (N_ / KC);

    v2f eta2[QQ / 2], l2[QQ / 2], cc2[QQ / 2];
    #pragma unroll
    for (int j = 0; j < QQ / 2; ++j) {
        eta2[j][0] = Eta[((size_t)(b * N_ + q0 + 2 * j)) * H_ + h];
        eta2[j][1] = Eta[((size_t)(b * N_ + q0 + 2 * j + 1)) * H_ + h];
        l2[j][0] = 0.f;  l2[j][1] = 0.f;
        cc2[j][0] = 0.f; cc2[j][1] = 0.f;
    }

    v2f kL2;  kL2[0] = LOG2E;  kL2[1] = LOG2E;
    v2f kNL2; kNL2[0] = -LOG2E; kNL2[1] = -LOG2E;

    const float4* kp = kv + ((size_t)(b * N_ + k0)) * H_ + h;

    #pragma unroll 4
    for (int k = 0; k < N_ / KC; ++k) {
        float4 v = kp[(size_t)k * H_];          // {Et, M, M*hv, 0}
        v2f vx; vx[0] = v.x; vx[1] = v.x;
        v2f vy; vy[0] = v.y; vy[1] = v.y;
        v2f vz; vz[0] = v.z; vz[1] = v.z;
        #pragma unroll
        for (int j = 0; j < QQ / 2; ++j) {
            v2f e2, a2;
            asm("v_pk_mul_f32 %0, %1, %2"
                : "=v"(e2) : "v"(eta2[j]), "v"(vx));
            asm("v_pk_fma_f32 %0, %1, %2, %3"
                : "=v"(a2) : "v"(e2), "v"(kL2), "v"(kNL2));
            float pn0 = __builtin_amdgcn_exp2f(a2[0]);
            float pn1 = __builtin_amdgcn_exp2f(a2[1]);
            v2f p0;
            p0[0] = __builtin_amdgcn_fmed3f(1.0f, e2[0], pn0);
            p0[1] = __builtin_amdgcn_fmed3f(1.0f, e2[1], pn1);
            asm("v_pk_fma_f32 %0, %1, %2, %0"
                : "+v"(l2[j]) : "v"(p0), "v"(vy));
            asm("v_pk_fma_f32 %0, %1, %2, %0"
                : "+v"(cc2[j]) : "v"(p0), "v"(vz));
        }
    }

    #pragma unroll
    for (int j = 0; j < QQ / 2; ++j) {
        accum[((size_t)c * (B_ * N_) + b * N_ + q0 + 2 * j) * H_ + h] =
            make_float2(l2[j][0], cc2[j][0]);
        accum[((size_t)c * (B_ * N_) + b * N_ + q0 + 2 * j + 1) * H_ + h] =
            make_float2(l2[j][1], cc2[j][1]);
    }
}

__global__ void fin3(const float2* __restrict__ accum, float* __restrict__ out) {
    const int idx = blockIdx.x * 256 + threadIdx.x;   // B*N*H threads
    float L = 0.f, C = 0.f;
    #pragma unroll
    for (int c = 0; c < KC; ++c) {
        float2 a = accum[(size_t)c * (B_ * N_ * H_) + idx];
        L += a.x;
        C += a.y;
    }
    out[idx] = C / L;
}

extern "C" void kernel_launch(void* const* d_in, const int* in_sizes, int n_in,
                              void* d_out, int out_size, void* d_ws, size_t ws_size,
                              hipStream_t stream) {
    const float* word_vecs = (const float*)d_in[0];
    const float* mask      = (const float*)d_in[1];
    const float* Wx_w      = (const float*)d_in[2];
    const float* Wx_b      = (const float*)d_in[3];
    const float* Wa_w      = (const float*)d_in[4];
    const float* Wa_b      = (const float*)d_in[5];
    const float* Ua_w      = (const float*)d_in[6];
    const float* Ua_b      = (const float*)d_in[7];
    float* out = (float*)d_out;

    // workspace layout (16B aligned): ~21.3 MB total
    char* p = (char*)d_ws;
    float*  WxT4  = (float*)p;   p += (size_t)75 * 512 * 4;               // 153.6 KB
    float*  WaT4  = (float*)p;   p += (size_t)32 * 512 * 4;               // 64 KB
    float*  UaT4  = (float*)p;   p += (size_t)32 * 512 * 4;               // 64 KB
    float*  Eta   = (float*)p;   p += (size_t)B_ * N_ * H_ * 4;           // 1 MB
    float4* kv    = (float4*)p;  p += (size_t)B_ * N_ * H_ * 16;          // 4 MB
    float2* accum = (float2*)p;  p += (size_t)KC * B_ * N_ * H_ * 8;      // 16 MB

    pack_all<<<IND_ + 2 * H_, 128, 0, stream>>>(Wx_w, Wa_w, Ua_w, WxT4, WaT4, UaT4);

    prep3<<<(B_ * N_) / RPB, 256, 0, stream>>>(word_vecs, WxT4, Wx_b,
                                               WaT4, Wa_b, UaT4, Ua_b,
                                               mask, Eta, kv);

    dim3 grid(KC, N_ / QQ, B_);
    attn3<<<grid, 128, 0, stream>>>(Eta, kv, accum);

    fin3<<<(B_ * N_ * H_) / 256, 256, 0, stream>>>(accum, out);
}